// Round 3
// baseline (290.533 us; speedup 1.0000x reference)
//
#include <hip/hip_runtime.h>

// Problem: N=65536 rows, C=100 classes, 6 matrices (outputs1..5, mimic).
// out[0]            = max over ALL elements of outputs1..5
// out[1 + row*6 + j]= softmax_j(margins(row)/TEMP), TEMP=2
// margin(x,t) = (x[t] == max(x)) ? max(x) - second_max(x) : 0

constexpr int C = 100;            // classes per row (C/2 = 50 float2 lanes)
constexpr float INV_TEMP = 0.5f;  // 1/TEMP

// Order-preserving float -> unsigned encoding (for atomicMax on any-sign floats)
__device__ __forceinline__ unsigned enc_f(float f) {
    unsigned u = __float_as_uint(f);
    return (u & 0x80000000u) ? ~u : (u | 0x80000000u);
}

// ws[0] = encoded running max; init to encoded -inf (0x007FFFFF).
__global__ void setup_kernel(unsigned* __restrict__ ws) {
    ws[0] = 0x007FFFFFu;
}

__global__ __launch_bounds__(256) void margin_softmax_kernel(
    const float* __restrict__ o1, const float* __restrict__ o2,
    const float* __restrict__ o3, const float* __restrict__ o4,
    const float* __restrict__ o5, const float* __restrict__ mimic,
    const int* __restrict__ tgt, float* __restrict__ out,
    unsigned* __restrict__ ws, int n)
{
    const float* mats[6] = {o1, o2, o3, o4, o5, mimic};
    const int lane  = threadIdx.x & 63;
    const int wid   = (blockIdx.x * blockDim.x + threadIdx.x) >> 6;
    const int nwav  = (gridDim.x * blockDim.x) >> 6;

    // Per-wave int32-vs-int64 target layout detection (self-contained; no ws
    // dependency). int64 little-endian nonneg => odd 32-bit words all zero.
    // int32 layout: odd words are random 0..99 -> P(all 64 zero) ~ 1e-128.
    const int probe = tgt[2 * lane + 1];              // words 1..127 < n, safe
    const unsigned long long nz = __ballot(probe != 0);
    const int tstride = (nz == 0ull) ? 2 : 1;         // wave-uniform

    float gmax = -INFINITY;   // running max over outputs1..5 elements seen

    for (int row = wid; row < n; row += nwav) {
        const int t = tgt[(size_t)row * tstride];   // 0..99, wave-uniform
        float margins[6];
        #pragma unroll
        for (int m = 0; m < 6; ++m) {
            const float* p = mats[m] + (size_t)row * C;
            float a = -INFINITY, b = -INFINITY;
            if (lane < C / 2) {
                float2 v = ((const float2*)p)[lane];   // one 400B wave read
                a = v.x; b = v.y;
            }
            // per-lane top2
            float m1 = fmaxf(a, b), m2 = fminf(a, b);
            // target value: element t lives in lane t/2, component t&1 (uniform t)
            float sel = (t & 1) ? b : a;
            float tv  = __shfl(sel, t >> 1);
            // wave butterfly top2 reduction (all lanes end with row top2)
            #pragma unroll
            for (int s = 1; s < 64; s <<= 1) {
                float q1 = __shfl_xor(m1, s);
                float q2 = __shfl_xor(m2, s);
                m2 = fmaxf(fminf(m1, q1), fmaxf(m2, q2));
                m1 = fmaxf(m1, q1);
            }
            margins[m] = (tv == m1) ? (m1 - m2) * INV_TEMP : 0.0f;
            if (m < 5) gmax = fmaxf(gmax, m1);   // mimic excluded from max_preds
        }
        // softmax over the 6 (already /TEMP) margins — identical on all lanes
        float mx = margins[0];
        #pragma unroll
        for (int j = 1; j < 6; ++j) mx = fmaxf(mx, margins[j]);
        float e[6], s = 0.0f;
        #pragma unroll
        for (int j = 0; j < 6; ++j) { e[j] = __expf(margins[j] - mx); s += e[j]; }
        float inv = 1.0f / s;
        if (lane < 6) out[1 + (size_t)row * 6 + lane] = e[lane] * inv;
    }

    // gmax is wave-uniform (m1 uniform after butterfly); one atomic per wave
    if (lane == 0) atomicMax(ws, enc_f(gmax));
}

__global__ void finalize_kernel(const unsigned* __restrict__ ws, float* __restrict__ out) {
    unsigned e = ws[0];
    unsigned bits = (e & 0x80000000u) ? (e & 0x7FFFFFFFu) : ~e;
    out[0] = __uint_as_float(bits);
}

extern "C" void kernel_launch(void* const* d_in, const int* in_sizes, int n_in,
                              void* d_out, int out_size, void* d_ws, size_t ws_size,
                              hipStream_t stream) {
    const float* o1    = (const float*)d_in[0];
    const float* o2    = (const float*)d_in[1];
    const float* o3    = (const float*)d_in[2];
    const float* o4    = (const float*)d_in[3];
    const float* o5    = (const float*)d_in[4];
    const float* mimic = (const float*)d_in[5];
    const int*   tgt   = (const int*)d_in[6];
    float*       out   = (float*)d_out;
    unsigned*    ws    = (unsigned*)d_ws;

    const int n = in_sizes[6];   // N = 65536 (targets element count)

    setup_kernel<<<1, 1, 0, stream>>>(ws);
    // 2048 blocks x 256 threads = 8192 waves -> 8 rows/wave grid-stride
    margin_softmax_kernel<<<2048, 256, 0, stream>>>(o1, o2, o3, o4, o5, mimic,
                                                    tgt, out, ws, n);
    finalize_kernel<<<1, 1, 0, stream>>>(ws, out);
}

// Round 4
// 204.487 us; speedup vs baseline: 1.4208x; 1.4208x over previous
//
#include <hip/hip_runtime.h>

// Problem: N=65536 rows, C=100 classes, 6 matrices (outputs1..5, mimic).
// out[0]            = max over ALL elements of outputs1..5
// out[1 + row*6 + j]= softmax_j(margins(row)/TEMP), TEMP=2
// margin(x,t) = (x[t] == max(x)) ? max(x) - second_max(x) : 0
//
// R3 post-mortem: wave-per-row butterfly was shuffle-latency-bound
// (167 us, 508 GB/s, VALUBusy 19%). This version: THREAD-per-row, no
// cross-lane ops in the hot path; 25 float4 loads/matrix/row; two
// independent top-2 accumulator pairs to break the fmax chain.

constexpr int C = 100;            // classes per row (25 float4)
constexpr float INV_TEMP = 0.5f;  // 1/TEMP

// Order-preserving float -> unsigned encoding (for atomicMax on any-sign floats)
__device__ __forceinline__ unsigned enc_f(float f) {
    unsigned u = __float_as_uint(f);
    return (u & 0x80000000u) ? ~u : (u | 0x80000000u);
}

// ws[0] = encoded running max; init to encoded -inf (0x007FFFFF).
__global__ void setup_kernel(unsigned* __restrict__ ws) {
    ws[0] = 0x007FFFFFu;
}

__global__ __launch_bounds__(256) void margin_softmax_kernel(
    const float* __restrict__ o1, const float* __restrict__ o2,
    const float* __restrict__ o3, const float* __restrict__ o4,
    const float* __restrict__ o5, const float* __restrict__ mimic,
    const int* __restrict__ tgt, float* __restrict__ out,
    unsigned* __restrict__ ws, int n)
{
    const float* mats[6] = {o1, o2, o3, o4, o5, mimic};
    const int tid  = blockIdx.x * blockDim.x + threadIdx.x;   // row
    const int lane = threadIdx.x & 63;

    // int32-vs-int64 target layout detection (wave-uniform, self-contained).
    // int64 little-endian nonneg => odd 32-bit words all zero. idx<n is safe
    // for both layouts (int64 buffer has 2n words).
    const int idx   = 2 * lane + 1;
    const int probe = (idx < n) ? tgt[idx] : 0;
    const unsigned long long nz = __ballot(probe != 0);
    const int tstride = (nz == 0ull) ? 2 : 1;

    float gmax = -INFINITY;   // running max over outputs1..5 row maxima

    if (tid < n) {
        const size_t rowoff = (size_t)tid * C;
        const int t = tgt[(size_t)tid * tstride];   // 0..99

        float margins[6];
        #pragma unroll
        for (int m = 0; m < 6; ++m) {
            const float4* __restrict__ p4 = (const float4*)(mats[m] + rowoff);
            // two independent top-2 trackers (halve the dependence chain)
            float m1a = -INFINITY, m2a = -INFINITY;
            float m1b = -INFINITY, m2b = -INFINITY;
            #pragma unroll
            for (int i = 0; i < C / 4; ++i) {
                float4 v = p4[i];
                m2a = fmaxf(m2a, fminf(m1a, v.x)); m1a = fmaxf(m1a, v.x);
                m2b = fmaxf(m2b, fminf(m1b, v.y)); m1b = fmaxf(m1b, v.y);
                m2a = fmaxf(m2a, fminf(m1a, v.z)); m1a = fmaxf(m1a, v.z);
                m2b = fmaxf(m2b, fminf(m1b, v.w)); m1b = fmaxf(m1b, v.w);
            }
            // merge the two trackers
            const float m1 = fmaxf(m1a, m1b);
            const float m2 = fmaxf(fminf(m1a, m1b), fmaxf(m2a, m2b));
            const float tv = mats[m][rowoff + t];   // L1-hit (row just read)
            margins[m] = (tv == m1) ? (m1 - m2) * INV_TEMP : 0.0f;
            if (m < 5) gmax = fmaxf(gmax, m1);      // mimic excluded
        }

        // softmax over the 6 (already /TEMP) margins
        float mx = margins[0];
        #pragma unroll
        for (int j = 1; j < 6; ++j) mx = fmaxf(mx, margins[j]);
        float e[6], s = 0.0f;
        #pragma unroll
        for (int j = 0; j < 6; ++j) { e[j] = __expf(margins[j] - mx); s += e[j]; }
        const float inv = 1.0f / s;
        #pragma unroll
        for (int j = 0; j < 6; ++j) out[1 + (size_t)tid * 6 + j] = e[j] * inv;
    }

    // wave-reduce the row maxima; one atomic per wave (lanes with tid>=n hold -inf)
    #pragma unroll
    for (int s = 1; s < 64; s <<= 1) gmax = fmaxf(gmax, __shfl_xor(gmax, s));
    if (lane == 0) atomicMax(ws, enc_f(gmax));
}

__global__ void finalize_kernel(const unsigned* __restrict__ ws, float* __restrict__ out) {
    unsigned e = ws[0];
    unsigned bits = (e & 0x80000000u) ? (e & 0x7FFFFFFFu) : ~e;
    out[0] = __uint_as_float(bits);
}

extern "C" void kernel_launch(void* const* d_in, const int* in_sizes, int n_in,
                              void* d_out, int out_size, void* d_ws, size_t ws_size,
                              hipStream_t stream) {
    const float* o1    = (const float*)d_in[0];
    const float* o2    = (const float*)d_in[1];
    const float* o3    = (const float*)d_in[2];
    const float* o4    = (const float*)d_in[3];
    const float* o5    = (const float*)d_in[4];
    const float* mimic = (const float*)d_in[5];
    const int*   tgt   = (const int*)d_in[6];
    float*       out   = (float*)d_out;
    unsigned*    ws    = (unsigned*)d_ws;

    const int n = in_sizes[6];   // N = 65536

    setup_kernel<<<1, 1, 0, stream>>>(ws);
    const int blocks = (n + 255) / 256;   // one thread per row
    margin_softmax_kernel<<<blocks, 256, 0, stream>>>(o1, o2, o3, o4, o5, mimic,
                                                      tgt, out, ws, n);
    finalize_kernel<<<1, 1, 0, stream>>>(ws, out);
}